// Round 1
// baseline (388.099 us; speedup 1.0000x reference)
//
#include <hip/hip_runtime.h>

#define NN 256
#define BIGF 1e8f

__global__ void zero_out_k(float* out) {
    if (threadIdx.x == 0) out[0] = 0.0f;
}

__global__ __launch_bounds__(256)
void dilate_dp_k(const float* __restrict__ pred, const float* __restrict__ target,
                 float* __restrict__ Rws, float* __restrict__ out) {
    const float GAM  = 0.01f;
    const float INVG = 100.0f;

    __shared__ float sP[NN + 2], sT[NN + 2];
    __shared__ float rb0[NN + 2], rb1[NN + 2], rb2[NN + 2];
    __shared__ float eb0[NN + 2], eb1[NN + 2], eb2[NN + 2];

    const int tid = threadIdx.x;
    const int b   = blockIdx.x;
    const int i   = tid + 1;                 // DP row this thread owns (1..N)
    const size_t base = (size_t)b * (NN * NN);

    // load series into LDS (D computed on the fly from these)
    sP[tid] = pred[b * NN + tid];
    sT[tid] = target[b * NN + tid];
    if (tid < 2) { sP[NN + tid] = 0.0f; sT[NN + tid] = 0.0f; }

    // forward init: rb0 <-> diag s=0 (R[0,0]=0), rb1 <-> diag s=1 (borders BIG)
    rb0[tid] = BIGF; rb1[tid] = BIGF; rb2[tid] = BIGF;
    if (tid < 2) { rb0[NN + tid] = BIGF; rb1[NN + tid] = BIGF; rb2[NN + tid] = BIGF; }
    __syncthreads();
    if (tid == 0) rb0[0] = 0.0f;
    __syncthreads();

    float* prev2 = rb0;  // diag s-2
    float* prev  = rb1;  // diag s-1
    float* cur   = rb2;  // diag s (written)
    int   off  = 0;      // packed offset of diag s within this batch's R store
    float rNN  = 0.0f;   // valid in thread 255 after the loop

    // ---------------- forward wavefront ----------------
    for (int s = 2; s <= 2 * NN; ++s) {
        int ilo = s - NN; if (ilo < 1) ilo = 1;
        int ihi = s - 1;  if (ihi > NN) ihi = NN;
        float val = BIGF;                    // sentinel for inactive rows
        if (i >= ilo && i <= ihi) {
            int j = s - i;
            float d  = sT[i - 1] - sP[j - 1]; d *= d;
            float dg = prev2[i - 1];         // R[i-1, j-1]
            float up = prev[i - 1];          // R[i-1, j]
            float lf = prev[i];              // R[i,   j-1]
            float m  = fminf(dg, fminf(up, lf));
            float z  = __expf((m - dg) * INVG) + __expf((m - up) * INVG)
                     + __expf((m - lf) * INVG);
            val = d + m - GAM * __logf(z);
            Rws[base + off + (i - ilo)] = val;   // coalesced diagonal store
        }
        cur[i] = val;
        if (tid == 0) cur[0] = BIGF;         // row-0 border stays BIG
        if (i == NN && s == 2 * NN) rNN = val;
        off += ihi - ilo + 1;
        __syncthreads();
        float* t0 = prev2; prev2 = prev; prev = cur; cur = t0;
    }

    // ---------------- backward init ----------------
    // R child buffers sentinel -BIG (=> weight exactly 0), E buffers 0
    rb0[tid] = -BIGF; rb1[tid] = -BIGF; rb2[tid] = -BIGF;
    eb0[tid] = 0.0f;  eb1[tid] = 0.0f;  eb2[tid] = 0.0f;
    if (tid < 2) {
        rb0[NN + tid] = -BIGF; rb1[NN + tid] = -BIGF; rb2[NN + tid] = -BIGF;
        eb0[NN + tid] = 0.0f;  eb1[NN + tid] = 0.0f;  eb2[NN + tid] = 0.0f;
    }
    __syncthreads();

    prev2 = rb0; prev = rb1; cur = rb2;      // R diag s+2, s+1, s
    float* ep2 = eb0; float* ep = eb1; float* ec = eb2;  // E same roles
    float accw = 0.0f;                       // sum E[i,j]*(i-j)^2 (this thread)

    // ---------------- backward wavefront ----------------
    for (int s = 2 * NN; s >= 2; --s) {
        int ilo = s - NN; if (ilo < 1) ilo = 1;
        int ihi = s - 1;  if (ihi > NN) ihi = NN;
        off -= ihi - ilo + 1;                // offset of diag s
        float rv = -BIGF, ev = 0.0f;
        if (i >= ilo && i <= ihi) {
            int j = s - i;
            rv = Rws[base + off + (i - ilo)];   // coalesced read, L2-hot
            if (s == 2 * NN) {
                ev = 1.0f;                      // E[N,N] seed
            } else {
                float rdn = prev[i + 1];        // R[i+1, j]
                float rrt = prev[i];            // R[i,   j+1]
                float rdg = prev2[i + 1];       // R[i+1, j+1]
                float ddn = sT[i]     - sP[j - 1]; ddn *= ddn;  // D[i+1, j]
                float drt = sT[i - 1] - sP[j];     drt *= drt;  // D[i,   j+1]
                float ddg = sT[i]     - sP[j];     ddg *= ddg;  // D[i+1, j+1]
                ev = __expf((rdn - rv - ddn) * INVG) * ep[i + 1]
                   + __expf((rrt - rv - drt) * INVG) * ep[i]
                   + __expf((rdg - rv - ddg) * INVG) * ep2[i + 1];
            }
            int dj = i - j;
            accw += ev * (float)(dj * dj);
        }
        cur[i] = rv;   // inactive rows re-write sentinels every step (no staleness)
        ec[i]  = ev;
        __syncthreads();
        float* t0 = prev2; prev2 = prev; prev = cur; cur = t0;
        float* t1 = ep2;   ep2   = ep;   ep   = ec;  ec  = t1;
    }

    // ---------------- block reduction + output ----------------
    for (int o = 32; o >= 1; o >>= 1) accw += __shfl_down(accw, o, 64);
    __syncthreads();                          // rotating buffers now reusable
    if ((tid & 63) == 0) eb0[tid >> 6] = accw;
    if (i == NN) eb0[8] = rNN;                // thread 255 parks R[N,N]
    __syncthreads();
    if (tid == 0) {
        float s4 = eb0[0] + eb0[1] + eb0[2] + eb0[3];
        const float SH = 0.8f / 128.0f;              // alpha / B
        const float TM = 0.2f / (128.0f * 65536.0f); // (1-alpha) / (B*N*N)
        atomicAdd(out, SH * eb0[8] + TM * s4);
    }
}

extern "C" void kernel_launch(void* const* d_in, const int* in_sizes, int n_in,
                              void* d_out, int out_size, void* d_ws, size_t ws_size,
                              hipStream_t stream) {
    const float* pred   = (const float*)d_in[0];
    const float* target = (const float*)d_in[1];
    float* out = (float*)d_out;
    float* Rws = (float*)d_ws;   // needs 128*256*256*4 = 33.6 MB

    zero_out_k<<<1, 64, 0, stream>>>(out);
    dilate_dp_k<<<128, 256, 0, stream>>>(pred, target, Rws, out);
}